// Round 13
// baseline (23.309 us; speedup 1.0000x reference)
//
#include <hip/hip_runtime.h>

#define BB 8
#define HH 64
#define WW 2048
#define HW (HH * WW)
#define NC 20

// R13: 4 pixels per thread, barrier-free, LDS-free. Block = 256 thr = 4 waves;
// wave = one image row, 64 lanes x 4 px = 256 cols. Grid (8,16,8) = 1024
// blocks = 4 blocks/CU -> whole grid co-resident (needs VGPR<=128), no tail.
//
// Window: 5 rows x 12 cols per thread via aligned float4 (gx0 = 4*lane =>
// gx0-4 is 16B-aligned). Zero-filled OOB = exact reference unfold pad.
// Gate (exact, monotone, R11/R12-proven): accumulate the reference fma chain
// for tap row jyS = max(0,2-gy) (rows before it are conv-masked exact no-ops);
// prefix>1 => final>1 => neighbor votes NC => top-5 = {self, NCx4} => own
// label. Shared math: masked |diff| for (k, s=p+jx) is pixel-independent ->
// ad[8] computed once per k, 20 fmas consume it. No dist[] array on the fast
// path: per-k d folds into a single running min (exact, order-free).
// Gate-fail waves (P~1e-5, wave-uniform) run R12's validated slow path.

__device__ __forceinline__ float gdepth(const float* __restrict__ Db, int y, int x) {
    // exact reference unfold zero-pad
    return ((unsigned)y < (unsigned)HH && (unsigned)x < (unsigned)WW)
               ? Db[y * WW + x] : 0.0f;
}

template <bool EDGE>
__device__ __forceinline__ float gate_min(const float win[5][12],
                                          const float wjs[5],
                                          const float mxm[8]) {
    float mn = 3.4e38f;
#pragma unroll
    for (int ky = 0; ky < 5; ++ky) {
#pragma unroll
        for (int kx = 0; kx < 5; ++kx) {
            if (ky == 2 && kx == 2) continue;   // self: dist exactly +0.0
            // masked |diff| shared by all 4 pixels (s = p + jx)
            float ad[8];
#pragma unroll
            for (int s = 0; s < 8; ++s) {
                const int cn = s + kx, ca = s + 2;
                const int nlin = ky * 12 + cn, alin = 2 * 12 + ca;
                // canonical operand order: |x-y|==|y-x| bit-exact, fixed CSE
                const float diff = (nlin > alin) ? (win[ky][cn] - win[2][ca])
                                                 : (win[2][ca] - win[ky][cn]);
                ad[s] = EDGE ? fabsf(diff) * mxm[s]   // exact *1.0/*0.0
                             : fabsf(diff);           // abs folds into fma mod
            }
#pragma unroll
            for (int p = 0; p < 4; ++p) {
                float d = 0.0f;                        // ref chain: jx ascending
#pragma unroll
                for (int jx = 0; jx < 5; ++jx)
                    d = fmaf(wjs[jx], ad[p + jx], d);
                mn = fminf(mn, d);                     // exact, order-free
            }
        }
    }
    return mn;
}

__global__ __launch_bounds__(256) void knn_refine(
    const float* __restrict__ depth,
    const int*   __restrict__ label,
    const float* __restrict__ wker,
    int*         __restrict__ out)
{
    const int t    = threadIdx.x;
    const int lane = t & 63;
    const int b    = blockIdx.z;
    const int gy   = blockIdx.y * 4 + (t >> 6);        // wave-uniform
    const int gx0  = blockIdx.x * 256 + lane * 4;      // 4 px: gx0..gx0+3

    const float* Db = depth + (size_t)b * HW;
    const int*   Lb = label + (size_t)b * HW;

    // own labels for the 4 px: one aligned int4 (k=12 dist==+0.0 is always
    // the first top-k pick: strict-< scan, ties -> lower k = lax.top_k)
    const int4 lab4 = *reinterpret_cast<const int4*>(Lb + gy * WW + gx0);

    const int  jyS  = (gy < 2) ? (2 - gy) : 0;   // first unmasked tap row
    const int  rtop = gy + jyS - 4;              // window top image row
    const bool edge = (blockIdx.x == 0) | (blockIdx.x == 7);  // block-uniform

    // gate-row weights: uniform address -> scalar loads
    float wjs[5];
#pragma unroll
    for (int jx = 0; jx < 5; ++jx) wjs[jx] = wker[jyS * 5 + jx];

    // ---- 5x12 window (exact zero-pad) ----
    float win[5][12];
    if (!edge) {
#pragma unroll
        for (int r = 0; r < 5; ++r) {
            const int ry = rtop + r;
            if ((unsigned)ry < (unsigned)HH) {        // wave-uniform branch
                const float4* rp =
                    reinterpret_cast<const float4*>(Db + ry * WW + (gx0 - 4));
                const float4 v0 = rp[0], v1 = rp[1], v2 = rp[2];
                win[r][0] = v0.x; win[r][1] = v0.y; win[r][2]  = v0.z; win[r][3]  = v0.w;
                win[r][4] = v1.x; win[r][5] = v1.y; win[r][6]  = v1.z; win[r][7]  = v1.w;
                win[r][8] = v2.x; win[r][9] = v2.y; win[r][10] = v2.z; win[r][11] = v2.w;
            } else {
#pragma unroll
                for (int c = 0; c < 12; ++c) win[r][c] = 0.0f;
            }
        }
    } else {
#pragma unroll
        for (int r = 0; r < 5; ++r) {
            const int ry = rtop + r;
#pragma unroll
            for (int c = 0; c < 12; ++c)
                win[r][c] = gdepth(Db, ry, gx0 - 4 + c);
        }
    }

    // anchor-col masks (edge blocks only; exact 0/1): anchor x = gx0 + s - 2
    float mxm[8];
    if (edge) {
#pragma unroll
        for (int s = 0; s < 8; ++s)
            mxm[s] = ((unsigned)(gx0 + s - 2) < (unsigned)WW) ? 1.0f : 0.0f;
    }

    const float mn = edge ? gate_min<true>(win, wjs, mxm)
                          : gate_min<false>(win, wjs, mxm);

    if (__all(mn > 1.0f)) {                     // prefix>1 => final>1 (monotone)
        *reinterpret_cast<int4*>(out + (size_t)b * HW + gy * WW + gx0) = lab4;
        return;
    }

    // ---- slow path (rare, wave-uniform): R12's validated full recompute ----
#pragma clang loop unroll(disable)
    for (int p = 0; p < 4; ++p) {
        const int gx = gx0 + p;

        float mxp[5];
#pragma unroll
        for (int d = 0; d < 5; ++d)
            mxp[d] = ((unsigned)(gx + d - 2) < (unsigned)WW) ? 1.0f : 0.0f;

        float dist[25];
#pragma unroll
        for (int k = 0; k < 25; ++k) dist[k] = 0.0f;

#pragma clang loop unroll(disable)
        for (int jy = 0; jy < 5; ++jy) {
            float row[5][9];                    // statically indexed only
#pragma unroll
            for (int r = 0; r < 5; ++r)
#pragma unroll
                for (int c = 0; c < 9; ++c)
                    row[r][c] = gdepth(Db, gy + jy + r - 4, gx + c - 4);
            const float myy =
                ((unsigned)(gy + jy - 2) < (unsigned)HH) ? 1.0f : 0.0f;
#pragma unroll
            for (int jx = 0; jx < 5; ++jx) {
                const float wj = myy * mxp[jx] * wker[jy * 5 + jx];
                const float Dq = row[2][jx + 2];
#pragma unroll
                for (int k = 0; k < 25; ++k) {
                    if (k == 12) continue;
                    const int ky = k / 5, kx = k % 5;
                    const int nlin = ky * 9 + jx + kx, alin = 18 + jx + 2;
                    const float diff = (nlin > alin) ? (row[ky][jx + kx] - Dq)
                                                     : (Dq - row[ky][jx + kx]);
                    dist[k] = fmaf(wj, fabsf(diff), dist[k]);
                }
            }
        }

        int labs[5];
        labs[0] = Lb[gy * WW + gx];
#pragma unroll
        for (int r = 1; r < 5; ++r) {
            float best = 3.4e38f;
            int bi = 0;
#pragma unroll
            for (int k = 0; k < 25; ++k) {
                if (k == 12) continue;
                if (dist[k] < best) { best = dist[k]; bi = k; }
            }
            int ky = (bi * 205) >> 10, kx = bi - ky * 5;   // bi/5, bi%5
            int ny = gy + ky - 2, nx = gx + kx - 2;
            // label unfold zero-pad: OOB neighbor label = 0
            int lv = ((unsigned)ny < (unsigned)HH && (unsigned)nx < (unsigned)WW)
                         ? Lb[ny * WW + nx] : 0;
            labs[r] = (best > 1.0f) ? NC : lv;
            if (r < 4) {
#pragma unroll
                for (int k = 0; k < 25; ++k) {
                    if (k == 12) continue;
                    if (k == bi) dist[k] = 3.4e38f;
                }
            }
        }

        int bestLab = 0, bestCnt = 0;
#pragma unroll
        for (int i = 0; i < 5; ++i) {
            const int li = labs[i];
            int c = 0;
#pragma unroll
            for (int j = 0; j < 5; ++j) c += (labs[j] == li) ? 1 : 0;
            if (li < NC && (c > bestCnt || (c == bestCnt && li < bestLab))) {
                bestCnt = c;
                bestLab = li;
            }
        }
        out[(size_t)b * HW + (size_t)gy * WW + gx] = bestLab;
    }
}

extern "C" void kernel_launch(void* const* d_in, const int* in_sizes, int n_in,
                              void* d_out, int out_size, void* d_ws, size_t ws_size,
                              hipStream_t stream) {
    const float* depth = (const float*)d_in[0];
    const int*   label = (const int*)d_in[1];
    const float* wker  = (const float*)d_in[2];
    int*         out   = (int*)d_out;

    knn_refine<<<dim3(8, 16, BB), dim3(256), 0, stream>>>(depth, label, wker, out);
}

// Round 14
// 12.377 us; speedup vs baseline: 1.8832x; 1.8832x over previous
//
#include <hip/hip_runtime.h>

#define BB 8
#define HH 64
#define WW 2048
#define HW (HH * WW)
#define NC 20
#define NXB 8

// R14: 4 px/thread, barrier-free, LDS-free, EDGE-BALANCED. Block = 256 thr =
// 4 waves; wave = one image row segment (64 lanes x 4 px). Grid (8,16,8) =
// 1024 blocks = 4/CU, single co-resident round -> time = slowest block.
// R13 lesson: edge blocks (25% of grid) ran a 108-scalar-load path ~2x the
// interior cost and set the kernel duration. R14 equalizes them:
//  - all lanes load 3 aligned float4/row from a CLAMPED base (only lane 0 of
//    block 0 / lane 63 of block 7 need it); the <=1 special lane per wave
//    repairs its window with a tiny divergent shift+zero fixup.
//  - conv x-masking folded into per-pixel weights wpe[p][jx] (select wjs or
//    0.0, 20 ops once per thread) -> gate inner math identical for all blocks.
// Gate (exact, monotone, R11-R13-proven): accumulate reference fma chain for
// tap row jyS=max(0,2-gy) (earlier rows are conv-masked exact no-ops);
// prefix>1 => final>1 => all neighbors vote NC => output own label.
// Gate-fail waves (P~1e-5) run R12's HW-validated per-pixel slow path.

__device__ __forceinline__ float gdepth(const float* __restrict__ Db, int y, int x) {
    // exact reference unfold zero-pad
    return ((unsigned)y < (unsigned)HH && (unsigned)x < (unsigned)WW)
               ? Db[y * WW + x] : 0.0f;
}

template <bool EDGE>
__device__ __forceinline__ float gate_min(const float win[5][12],
                                          const float wjs[5],
                                          const float wpe[4][5]) {
    float mn = 3.4e38f;
#pragma unroll
    for (int ky = 0; ky < 5; ++ky) {
#pragma unroll
        for (int kx = 0; kx < 5; ++kx) {
            if (ky == 2 && kx == 2) continue;   // self: dist exactly +0.0
            // |diff| shared by all 4 pixels (s = p + jx); abs folds into fma
            float ad[8];
#pragma unroll
            for (int s = 0; s < 8; ++s) {
                const int cn = s + kx, ca = s + 2;
                const int nlin = ky * 12 + cn, alin = 2 * 12 + ca;
                // canonical operand order: |x-y|==|y-x| bit-exact, fixed CSE
                const float diff = (nlin > alin) ? (win[ky][cn] - win[2][ca])
                                                 : (win[2][ca] - win[ky][cn]);
                ad[s] = fabsf(diff);
            }
#pragma unroll
            for (int p = 0; p < 4; ++p) {
                float d = 0.0f;                 // ref chain: jx ascending
#pragma unroll
                for (int jx = 0; jx < 5; ++jx)
                    d = fmaf(EDGE ? wpe[p][jx] : wjs[jx], ad[p + jx], d);
                mn = fminf(mn, d);              // exact, order-free
            }
        }
    }
    return mn;
}

__global__ __launch_bounds__(256) void knn_refine(
    const float* __restrict__ depth,
    const int*   __restrict__ label,
    const float* __restrict__ wker,
    int*         __restrict__ out)
{
    const int t    = threadIdx.x;
    const int lane = t & 63;
    const int b    = blockIdx.z;
    const int gy   = blockIdx.y * 4 + (t >> 6);        // wave-uniform
    const int gx0  = blockIdx.x * 256 + lane * 4;      // 4 px: gx0..gx0+3

    const float* Db = depth + (size_t)b * HW;
    const int*   Lb = label + (size_t)b * HW;

    // own labels for the 4 px (k=12 dist==+0.0 is always the first top-k
    // pick: strict-< scan, ties -> lower k = lax.top_k)
    const int4 lab4 = *reinterpret_cast<const int4*>(Lb + gy * WW + gx0);

    const int  jyS  = (gy < 2) ? (2 - gy) : 0;   // first unmasked tap row
    const int  rtop = gy + jyS - 4;              // window top image row
    const bool edge = (blockIdx.x == 0) | (blockIdx.x == NXB - 1);

    // gate-row weights: uniform address -> scalar loads (SGPR)
    float wjs[5];
#pragma unroll
    for (int jx = 0; jx < 5; ++jx) wjs[jx] = wker[jyS * 5 + jx];

    // clamped aligned load base; <=1 special lane per edge wave
    int base = gx0 - 4;
    const bool spec0 = base < 0;            // block 0, lane 0 only
    const bool spec7 = base > WW - 12;      // block 7, lane 63 only
    if (spec0) base = 0;                    // shift +4, stays 16B-aligned
    if (spec7) base = WW - 12;              // 2036,   stays 16B-aligned

    // ---- 5x12 window: 3 aligned float4 per in-range row, zeros elsewhere ----
    float win[5][12];
#pragma unroll
    for (int r = 0; r < 5; ++r) {
        const int ry = rtop + r;
        if ((unsigned)ry < (unsigned)HH) {          // wave-uniform branch
            const float4* rp =
                reinterpret_cast<const float4*>(Db + ry * WW + base);
            const float4 v0 = rp[0], v1 = rp[1], v2 = rp[2];
            win[r][0] = v0.x; win[r][1] = v0.y; win[r][2]  = v0.z; win[r][3]  = v0.w;
            win[r][4] = v1.x; win[r][5] = v1.y; win[r][6]  = v1.z; win[r][7]  = v1.w;
            win[r][8] = v2.x; win[r][9] = v2.y; win[r][10] = v2.z; win[r][11] = v2.w;
        } else {
#pragma unroll
            for (int c = 0; c < 12; ++c) win[r][c] = 0.0f;
        }
    }
    // divergent fixup (<=1 active lane/wave): realign window + zero-pad x-OOB
    if (spec0 | spec7) {
        if (spec0) {
#pragma unroll
            for (int r = 0; r < 5; ++r) {
#pragma unroll
                for (int c = 11; c >= 4; --c) win[r][c] = win[r][c - 4];
#pragma unroll
                for (int c = 0; c < 4; ++c)  win[r][c] = 0.0f;
            }
        } else {
#pragma unroll
            for (int r = 0; r < 5; ++r) {
#pragma unroll
                for (int c = 0; c < 8; ++c)  win[r][c] = win[r][c + 4];
#pragma unroll
                for (int c = 8; c < 12; ++c) win[r][c] = 0.0f;
            }
        }
    }

    // per-pixel masked weights (edge blocks only): conv zero-pad in p-space.
    // select (not multiply): fmaf(0, ad, acc) == acc bit-exactly.
    float wpe[4][5];
    if (edge) {
#pragma unroll
        for (int p = 0; p < 4; ++p)
#pragma unroll
            for (int jx = 0; jx < 5; ++jx) {
                const int ax = gx0 + p + jx - 2;
                wpe[p][jx] = ((unsigned)ax < (unsigned)WW) ? wjs[jx] : 0.0f;
            }
    }

    const float mn = edge ? gate_min<true>(win, wjs, wpe)
                          : gate_min<false>(win, wjs, wpe);

    if (__all(mn > 1.0f)) {                 // prefix>1 => final>1 (monotone)
        *reinterpret_cast<int4*>(out + (size_t)b * HW + gy * WW + gx0) = lab4;
        return;
    }

    // ---- slow path (rare, wave-uniform): R12's validated full recompute ----
#pragma clang loop unroll(disable)
    for (int p = 0; p < 4; ++p) {
        const int gx = gx0 + p;

        float mxp[5];
#pragma unroll
        for (int d = 0; d < 5; ++d)
            mxp[d] = ((unsigned)(gx + d - 2) < (unsigned)WW) ? 1.0f : 0.0f;

        float dist[25];
#pragma unroll
        for (int k = 0; k < 25; ++k) dist[k] = 0.0f;

#pragma clang loop unroll(disable)
        for (int jy = 0; jy < 5; ++jy) {
            float row[5][9];                // statically indexed only
#pragma unroll
            for (int r = 0; r < 5; ++r)
#pragma unroll
                for (int c = 0; c < 9; ++c)
                    row[r][c] = gdepth(Db, gy + jy + r - 4, gx + c - 4);
            const float myy =
                ((unsigned)(gy + jy - 2) < (unsigned)HH) ? 1.0f : 0.0f;
#pragma unroll
            for (int jx = 0; jx < 5; ++jx) {
                const float wj = myy * mxp[jx] * wker[jy * 5 + jx];
                const float Dq = row[2][jx + 2];
#pragma unroll
                for (int k = 0; k < 25; ++k) {
                    if (k == 12) continue;
                    const int ky = k / 5, kx = k % 5;
                    const int nlin = ky * 9 + jx + kx, alin = 18 + jx + 2;
                    const float diff = (nlin > alin) ? (row[ky][jx + kx] - Dq)
                                                     : (Dq - row[ky][jx + kx]);
                    dist[k] = fmaf(wj, fabsf(diff), dist[k]);
                }
            }
        }

        int labs[5];
        labs[0] = Lb[gy * WW + gx];
#pragma unroll
        for (int r = 1; r < 5; ++r) {
            float best = 3.4e38f;
            int bi = 0;
#pragma unroll
            for (int k = 0; k < 25; ++k) {
                if (k == 12) continue;
                if (dist[k] < best) { best = dist[k]; bi = k; }
            }
            int ky = (bi * 205) >> 10, kx = bi - ky * 5;   // bi/5, bi%5
            int ny = gy + ky - 2, nx = gx + kx - 2;
            // label unfold zero-pad: OOB neighbor label = 0
            int lv = ((unsigned)ny < (unsigned)HH && (unsigned)nx < (unsigned)WW)
                         ? Lb[ny * WW + nx] : 0;
            labs[r] = (best > 1.0f) ? NC : lv;
            if (r < 4) {
#pragma unroll
                for (int k = 0; k < 25; ++k) {
                    if (k == 12) continue;
                    if (k == bi) dist[k] = 3.4e38f;
                }
            }
        }

        int bestLab = 0, bestCnt = 0;
#pragma unroll
        for (int i = 0; i < 5; ++i) {
            const int li = labs[i];
            int c = 0;
#pragma unroll
            for (int j = 0; j < 5; ++j) c += (labs[j] == li) ? 1 : 0;
            if (li < NC && (c > bestCnt || (c == bestCnt && li < bestLab))) {
                bestCnt = c;
                bestLab = li;
            }
        }
        out[(size_t)b * HW + (size_t)gy * WW + gx] = bestLab;
    }
}

extern "C" void kernel_launch(void* const* d_in, const int* in_sizes, int n_in,
                              void* d_out, int out_size, void* d_ws, size_t ws_size,
                              hipStream_t stream) {
    const float* depth = (const float*)d_in[0];
    const int*   label = (const int*)d_in[1];
    const float* wker  = (const float*)d_in[2];
    int*         out   = (int*)d_out;

    knn_refine<<<dim3(NXB, 16, BB), dim3(256), 0, stream>>>(depth, label, wker, out);
}